// Round 5
// baseline (963.643 us; speedup 1.0000x reference)
//
#include <hip/hip_runtime.h>
#include <math.h>

// ---------------------------------------------------------------------------
// PGCN twin-branch GCN. fp32. R5: GEMM rewrite — 128x128 tile, 8x8/thread,
// transposed-A LDS staging (all-b128 reads), kc=32. Rest identical to R4.
// ---------------------------------------------------------------------------

#define TPB 256

__device__ __forceinline__ int swz_block(int bid, int nb) {
  int per = nb >> 3;
  return (bid & 7) * per + (bid >> 3);
}

__device__ __forceinline__ void f4fma(float4& a, const float4 b, float s) {
  a.x += b.x * s; a.y += b.y * s; a.z += b.z * s; a.w += b.w * s;
}
__device__ __forceinline__ float4 f4s(const float4 a, float s) {
  return make_float4(a.x * s, a.y * s, a.z * s, a.w * s);
}

// ---------------- CSR build ----------------
__global__ __launch_bounds__(TPB) void count_k(const int* __restrict__ col,
                                               int* __restrict__ cnt, int E) {
  int e = blockIdx.x * TPB + threadIdx.x;
  if (e < E) atomicAdd(&cnt[col[e]], 1);
}

__global__ __launch_bounds__(TPB) void scan1_k(const int* __restrict__ cnt,
                                               int* __restrict__ rowptr,
                                               int* __restrict__ bsum, int N) {
  __shared__ int s[TPB];
  int tid = threadIdx.x;
  int gid = blockIdx.x * TPB + tid;
  int v = (gid < N) ? cnt[gid] : 0;
  s[tid] = v;
  __syncthreads();
  for (int o = 1; o < TPB; o <<= 1) {
    int t = (tid >= o) ? s[tid - o] : 0;
    __syncthreads();
    s[tid] += t;
    __syncthreads();
  }
  if (gid < N) rowptr[gid] = s[tid] - v;
  if (tid == TPB - 1) bsum[blockIdx.x] = s[TPB - 1];
}

__global__ __launch_bounds__(TPB) void scan2_k(int* __restrict__ bsum, int nb) {
  __shared__ int s[TPB];
  int tid = threadIdx.x;
  int v = (tid < nb) ? bsum[tid] : 0;
  s[tid] = v;
  __syncthreads();
  for (int o = 1; o < TPB; o <<= 1) {
    int t = (tid >= o) ? s[tid - o] : 0;
    __syncthreads();
    s[tid] += t;
    __syncthreads();
  }
  if (tid < nb) bsum[tid] = s[tid] - v;
}

__global__ __launch_bounds__(TPB) void scan3_k(int* __restrict__ rowptr,
                                               const int* __restrict__ bsum,
                                               int N, int E) {
  int gid = blockIdx.x * TPB + threadIdx.x;
  if (gid < N) rowptr[gid] += bsum[blockIdx.x];
  if (gid == 0) rowptr[N] = E;
}

__global__ __launch_bounds__(TPB) void fill_k(const int* __restrict__ col,
                                              const int* __restrict__ rowptr,
                                              int* __restrict__ fil,
                                              int* __restrict__ csr, int E) {
  int e = blockIdx.x * TPB + threadIdx.x;
  if (e < E) {
    int c = col[e];
    int p = rowptr[c] + atomicAdd(&fil[c], 1);
    csr[p] = e;
  }
}

__global__ __launch_bounds__(TPB) void sortadj_k(const int* __restrict__ rowptr,
                                                 int* __restrict__ csr, int N) {
  int i = blockIdx.x * TPB + threadIdx.x;
  if (i >= N) return;
  int s = rowptr[i], e = rowptr[i + 1];
  for (int a = s + 1; a < e; ++a) {
    int v = csr[a];
    int b = a - 1;
    while (b >= s && csr[b] > v) { csr[b + 1] = csr[b]; --b; }
    csr[b + 1] = v;
  }
}

__global__ __launch_bounds__(TPB) void deg_k(const int* __restrict__ rowptr,
                                             const int* __restrict__ csr,
                                             const float* __restrict__ ea,
                                             float* __restrict__ dinv, int N) {
  int i = blockIdx.x * TPB + threadIdx.x;
  if (i >= N) return;
  int s = rowptr[i], e = rowptr[i + 1];
  float d0 = 1.f, d1 = 1.f, d2 = 1.f, d3 = 1.f;
  for (int j = s; j < e; ++j) {
    int eid = csr[j];
    float4 w = *reinterpret_cast<const float4*>(&ea[(size_t)eid * 4]);
    d0 += w.x; d1 += w.y; d2 += w.z; d3 += w.w;
  }
  float dO = (float)(e - s) + 1.f;
  dinv[0 * N + i] = 1.f / sqrtf(d0);
  dinv[1 * N + i] = 1.f / sqrtf(d1);
  dinv[2 * N + i] = 1.f / sqrtf(d2);
  dinv[3 * N + i] = 1.f / sqrtf(d3);
  dinv[4 * N + i] = 1.f / sqrtf(dO);
}

__global__ __launch_bounds__(TPB) void eresolve_k(
    const int* __restrict__ csr, const int* __restrict__ erow,
    const float* __restrict__ ea, const float* __restrict__ dinv, int N, int E,
    int* __restrict__ csrSrc, float4* __restrict__ csrW,
    float* __restrict__ csrWO) {
  int j = blockIdx.x * TPB + threadIdx.x;
  if (j >= E) return;
  int eid = csr[j];
  int r = erow[eid];
  float4 a = *reinterpret_cast<const float4*>(&ea[(size_t)eid * 4]);
  csrSrc[j] = r;
  csrW[j] = make_float4(a.x * dinv[r], a.y * dinv[N + r], a.z * dinv[2 * N + r],
                        a.w * dinv[3 * N + r]);
  csrWO[j] = dinv[4 * N + r];
}

// ------------- fused 4-channel gather on raw x -> S0..S3 ----------
__global__ __launch_bounds__(256) void gather4_k(
    const float4* __restrict__ X, const int* __restrict__ rowptr,
    const int* __restrict__ csrSrc, const float4* __restrict__ csrW,
    const float* __restrict__ dinv, int N, float4* __restrict__ S0,
    float4* __restrict__ S1, float4* __restrict__ S2, float4* __restrict__ S3) {
  int sb = swz_block(blockIdx.x, gridDim.x);
  int node = sb * 8 + (threadIdx.x >> 5);
  int l = threadIdx.x & 31;
  int s = rowptr[node], e = rowptr[node + 1];
  float d0 = dinv[node], d1 = dinv[N + node], d2 = dinv[2 * N + node],
        d3 = dinv[3 * N + node];
  float4 xs = X[(size_t)node * 32 + l];
  float4 a0 = f4s(xs, d0), a1 = f4s(xs, d1), a2 = f4s(xs, d2), a3 = f4s(xs, d3);
  int j = s;
  for (; j + 3 < e; j += 4) {
    int r0 = csrSrc[j], r1 = csrSrc[j + 1], r2 = csrSrc[j + 2], r3 = csrSrc[j + 3];
    float4 w0 = csrW[j], w1 = csrW[j + 1], w2 = csrW[j + 2], w3 = csrW[j + 3];
    float4 x0 = X[(size_t)r0 * 32 + l];
    float4 x1 = X[(size_t)r1 * 32 + l];
    float4 x2 = X[(size_t)r2 * 32 + l];
    float4 x3 = X[(size_t)r3 * 32 + l];
    f4fma(a0, x0, w0.x); f4fma(a1, x0, w0.y); f4fma(a2, x0, w0.z); f4fma(a3, x0, w0.w);
    f4fma(a0, x1, w1.x); f4fma(a1, x1, w1.y); f4fma(a2, x1, w1.z); f4fma(a3, x1, w1.w);
    f4fma(a0, x2, w2.x); f4fma(a1, x2, w2.y); f4fma(a2, x2, w2.z); f4fma(a3, x2, w2.w);
    f4fma(a0, x3, w3.x); f4fma(a1, x3, w3.y); f4fma(a2, x3, w3.z); f4fma(a3, x3, w3.w);
  }
  for (; j < e; ++j) {
    int r = csrSrc[j];
    float4 w = csrW[j];
    float4 xr = X[(size_t)r * 32 + l];
    f4fma(a0, xr, w.x); f4fma(a1, xr, w.y); f4fma(a2, xr, w.z); f4fma(a3, xr, w.w);
  }
  size_t o = (size_t)node * 32 + l;
  S0[o] = f4s(a0, d0);
  S1[o] = f4s(a1, d1);
  S2[o] = f4s(a2, d2);
  S3[o] = f4s(a3, d3);
}

// ------------- single-channel gather (ones weights) ----------
__global__ __launch_bounds__(256) void gather1_k(
    const float4* __restrict__ X, const int* __restrict__ rowptr,
    const int* __restrict__ csrSrc, const float* __restrict__ csrWO,
    const float* __restrict__ dinvO, int N, float4* __restrict__ Out) {
  int sb = swz_block(blockIdx.x, gridDim.x);
  int node = sb * 8 + (threadIdx.x >> 5);
  int l = threadIdx.x & 31;
  int s = rowptr[node], e = rowptr[node + 1];
  float di = dinvO[node];
  float4 acc = f4s(X[(size_t)node * 32 + l], di);
  int j = s;
  for (; j + 3 < e; j += 4) {
    int r0 = csrSrc[j], r1 = csrSrc[j + 1], r2 = csrSrc[j + 2], r3 = csrSrc[j + 3];
    float w0 = csrWO[j], w1 = csrWO[j + 1], w2 = csrWO[j + 2], w3 = csrWO[j + 3];
    float4 x0 = X[(size_t)r0 * 32 + l];
    float4 x1 = X[(size_t)r1 * 32 + l];
    float4 x2 = X[(size_t)r2 * 32 + l];
    float4 x3 = X[(size_t)r3 * 32 + l];
    f4fma(acc, x0, w0); f4fma(acc, x1, w1); f4fma(acc, x2, w2); f4fma(acc, x3, w3);
  }
  for (; j < e; ++j) {
    f4fma(acc, X[(size_t)csrSrc[j] * 32 + l], csrWO[j]);
  }
  Out[(size_t)node * 32 + l] = f4s(acc, di);
}

// ---------------- GEMM core helpers (128x128 tile, 8x8/thread) ----------------
// AsT[k][r] transposed staging (stride 132 pads row-groups onto disjoint banks).
#define GEMM_STAGE(Aptr)                                                        \
  {                                                                             \
    _Pragma("unroll")                                                           \
    for (int i = 0; i < 4; ++i) {                                               \
      int u = tid + i * 256;                                                    \
      int r = u >> 3, k4 = u & 7;                                               \
      float4 v = *reinterpret_cast<const float4*>(                              \
          &Aptr[(size_t)(rowBase + r) * 128 + kc + k4 * 4]);                    \
      AsT[k4 * 4 + 0][r] = v.x;                                                 \
      AsT[k4 * 4 + 1][r] = v.y;                                                 \
      AsT[k4 * 4 + 2][r] = v.z;                                                 \
      AsT[k4 * 4 + 3][r] = v.w;                                                 \
    }                                                                           \
    _Pragma("unroll")                                                           \
    for (int i = 0; i < 4; ++i) {                                               \
      int u = tid + i * 256;                                                    \
      int r = u >> 5, c4 = u & 31;                                              \
      *reinterpret_cast<float4*>(&Ws[r][c4 * 4]) =                              \
          *reinterpret_cast<const float4*>(&Wp[(size_t)(kc + r) * 128 + c4 * 4]);\
    }                                                                           \
  }

#define GEMM_COMPUTE()                                                          \
  _Pragma("unroll 8")                                                           \
  for (int k = 0; k < 32; ++k) {                                                \
    float a[8], b[8];                                                           \
    *reinterpret_cast<float4*>(&a[0]) =                                         \
        *reinterpret_cast<const float4*>(&AsT[k][ty * 8]);                      \
    *reinterpret_cast<float4*>(&a[4]) =                                         \
        *reinterpret_cast<const float4*>(&AsT[k][ty * 8 + 4]);                  \
    *reinterpret_cast<float4*>(&b[0]) =                                         \
        *reinterpret_cast<const float4*>(&Ws[k][tx * 8]);                       \
    *reinterpret_cast<float4*>(&b[4]) =                                         \
        *reinterpret_cast<const float4*>(&Ws[k][tx * 8 + 4]);                   \
    _Pragma("unroll")                                                           \
    for (int j = 0; j < 8; ++j) {                                               \
      _Pragma("unroll")                                                         \
      for (int c = 0; c < 8; ++c) acc[j][c] += a[j] * b[c];                     \
    }                                                                           \
  }

// C = act(A @ W + bias)
template <bool RELU>
__global__ __launch_bounds__(256) void gemm_epi(const float* __restrict__ A,
                                                const float* __restrict__ Wp,
                                                const float* __restrict__ bias,
                                                float* __restrict__ C, int M) {
  __shared__ float AsT[32][132];
  __shared__ float Ws[32][128];
  int tid = threadIdx.x;
  int tx = tid & 15;   // cols tx*8 .. +7
  int ty = tid >> 4;   // rows ty*8 .. +7
  int rowBase = blockIdx.x * 128;
  float acc[8][8] = {};
  for (int kc = 0; kc < 128; kc += 32) {
    GEMM_STAGE(A);
    __syncthreads();
    GEMM_COMPUTE();
    __syncthreads();
  }
  float bb[8];
  *reinterpret_cast<float4*>(&bb[0]) = *reinterpret_cast<const float4*>(&bias[tx * 8]);
  *reinterpret_cast<float4*>(&bb[4]) = *reinterpret_cast<const float4*>(&bias[tx * 8 + 4]);
#pragma unroll
  for (int j = 0; j < 8; ++j) {
    float o[8];
#pragma unroll
    for (int c = 0; c < 8; ++c) {
      float v = acc[j][c] + bb[c];
      o[c] = RELU ? fmaxf(v, 0.f) : v;
    }
    size_t r = (size_t)(rowBase + ty * 8 + j) * 128 + tx * 8;
    *reinterpret_cast<float4*>(&C[r]) = *reinterpret_cast<float4*>(&o[0]);
    *reinterpret_cast<float4*>(&C[r + 4]) = *reinterpret_cast<float4*>(&o[4]);
  }
}

// g1 = 0.25 * sum_q relu(S_q @ W_q + b_q)
__global__ __launch_bounds__(256) void gemm4_k(
    const float* __restrict__ S0, const float* __restrict__ S1,
    const float* __restrict__ S2, const float* __restrict__ S3,
    const float* __restrict__ W0, const float* __restrict__ W1,
    const float* __restrict__ W2, const float* __restrict__ W3,
    const float* __restrict__ B0, const float* __restrict__ B1,
    const float* __restrict__ B2, const float* __restrict__ B3,
    float* __restrict__ g1, int M) {
  __shared__ float AsT[32][132];
  __shared__ float Ws[32][128];
  const float* Sarr[4] = {S0, S1, S2, S3};
  const float* Warr[4] = {W0, W1, W2, W3};
  const float* Barr[4] = {B0, B1, B2, B3};
  int tid = threadIdx.x;
  int tx = tid & 15;
  int ty = tid >> 4;
  int rowBase = blockIdx.x * 128;
  float facc[8][8] = {};
  for (int q = 0; q < 4; ++q) {
    const float* A = Sarr[q];
    const float* Wp = Warr[q];
    float acc[8][8] = {};
    for (int kc = 0; kc < 128; kc += 32) {
      GEMM_STAGE(A);
      __syncthreads();
      GEMM_COMPUTE();
      __syncthreads();
    }
    float bb[8];
    *reinterpret_cast<float4*>(&bb[0]) =
        *reinterpret_cast<const float4*>(&Barr[q][tx * 8]);
    *reinterpret_cast<float4*>(&bb[4]) =
        *reinterpret_cast<const float4*>(&Barr[q][tx * 8 + 4]);
#pragma unroll
    for (int j = 0; j < 8; ++j)
#pragma unroll
      for (int c = 0; c < 8; ++c)
        facc[j][c] += fmaxf(acc[j][c] + bb[c], 0.f) * 0.25f;
  }
#pragma unroll
  for (int j = 0; j < 8; ++j) {
    size_t r = (size_t)(rowBase + ty * 8 + j) * 128 + tx * 8;
    *reinterpret_cast<float4*>(&g1[r]) = *reinterpret_cast<float4*>(&facc[j][0]);
    *reinterpret_cast<float4*>(&g1[r + 4]) = *reinterpret_cast<float4*>(&facc[j][4]);
  }
}

// ------------- score -------------
__global__ __launch_bounds__(256) void score_a(
    const float* __restrict__ g1, const float* __restrict__ g2,
    const float* __restrict__ g3, const float* __restrict__ Wrel,
    const float* __restrict__ Wroot, float* __restrict__ trel,
    float* __restrict__ troot, int N) {
  int wave = threadIdx.x >> 6;
  int lane = threadIdx.x & 63;
  int node = blockIdx.x * 4 + wave;
  if (node >= N) return;
  float sr = 0.f, so = 0.f;
#pragma unroll
  for (int t = 0; t < 2; ++t) {
    int f = lane + t * 64;
    float v1 = g1[(size_t)node * 128 + f];
    float v2 = g2[(size_t)node * 128 + f];
    float v3 = g3[(size_t)node * 128 + f];
    sr += v1 * Wrel[f] + v2 * Wrel[128 + f] + v3 * Wrel[256 + f];
    so += v1 * Wroot[f] + v2 * Wroot[128 + f] + v3 * Wroot[256 + f];
  }
  for (int off = 32; off; off >>= 1) {
    sr += __shfl_down(sr, off);
    so += __shfl_down(so, off);
  }
  if (lane == 0) { trel[node] = sr; troot[node] = so; }
}

__global__ __launch_bounds__(TPB) void score_b(
    const int* __restrict__ rowptr, const int* __restrict__ csrSrc,
    const float* __restrict__ trel, const float* __restrict__ troot,
    const float* __restrict__ bs, float* __restrict__ score, int N) {
  int i = blockIdx.x * TPB + threadIdx.x;
  if (i >= N) return;
  float sc = bs[0] + troot[i];
  int s = rowptr[i], e = rowptr[i + 1];
  for (int j = s; j < e; ++j) sc += trel[csrSrc[j]];
  score[i] = sc;
}

// ------------- per-graph top-k (bitonic) + tanh-weighted mean pool -------------
__global__ __launch_bounds__(512) void topk_pool(
    const float* __restrict__ score, const float* __restrict__ g1,
    const float* __restrict__ g2, const float* __restrict__ g3,
    float* __restrict__ r, int half, int npg, int k) {
  __shared__ float key[1024];
  __shared__ int idx[1024];
  __shared__ float wts[512];
  int b = blockIdx.x;
  int tid = threadIdx.x;
  int base = b * npg;
  for (int i = tid; i < 1024; i += 512) {
    key[i] = (i < npg) ? score[base + i] : -3.0e38f;
    idx[i] = i;
  }
  __syncthreads();
  for (int kk = 2; kk <= 1024; kk <<= 1) {
    for (int j = kk >> 1; j > 0; j >>= 1) {
      for (int i = tid; i < 1024; i += 512) {
        int ixj = i ^ j;
        if (ixj > i) {
          bool desc = ((i & kk) == 0);
          float ki = key[i], kj = key[ixj];
          bool sw = desc ? (ki < kj) : (ki > kj);
          if (sw) {
            key[i] = kj; key[ixj] = ki;
            int t = idx[i]; idx[i] = idx[ixj]; idx[ixj] = t;
          }
        }
      }
      __syncthreads();
    }
  }
  if (tid < k) wts[tid] = tanhf(key[tid]);
  __syncthreads();
  if (tid < 384) {
    const float* gp = (tid < 128) ? g1 : ((tid < 256) ? g2 : g3);
    int fo = tid & 127;
    float acc = 0.f;
    for (int j = 0; j < k; ++j) {
      int n = base + idx[j];
      acc += wts[j] * gp[(size_t)n * 128 + fo];
    }
    r[(size_t)b * 768 + half * 384 + tid] = acc / (float)k;
  }
}

// ------------- MLP 768 -> 32 -> 8 -> 2 -------------
__global__ __launch_bounds__(64) void mlp_k(
    const float* __restrict__ r, const float* __restrict__ Wm1,
    const float* __restrict__ bm1, const float* __restrict__ Wm2,
    const float* __restrict__ bm2, const float* __restrict__ Wm3,
    const float* __restrict__ bm3, float* __restrict__ out) {
  __shared__ float rr[768];
  __shared__ float h1[32];
  __shared__ float h2[8];
  int b = blockIdx.x;
  int tid = threadIdx.x;
  for (int i = tid; i < 768; i += 64) rr[i] = r[(size_t)b * 768 + i];
  __syncthreads();
  if (tid < 32) {
    float s = bm1[tid];
    for (int i = 0; i < 768; ++i) s += rr[i] * Wm1[i * 32 + tid];
    h1[tid] = fmaxf(s, 0.f);
  }
  __syncthreads();
  if (tid < 8) {
    float s = bm2[tid];
    for (int i = 0; i < 32; ++i) s += h1[i] * Wm2[i * 8 + tid];
    h2[tid] = fmaxf(s, 0.f);
  }
  __syncthreads();
  if (tid < 2) {
    float s = bm3[tid];
    for (int i = 0; i < 8; ++i) s += h2[i] * Wm3[i * 2 + tid];
    out[b * 2 + tid] = s;
  }
}

// ---------------------------------------------------------------------------
extern "C" void kernel_launch(void* const* d_in, const int* in_sizes, int n_in,
                              void* d_out, int out_size, void* d_ws, size_t ws_size,
                              hipStream_t stream) {
  const float* x[2]  = {(const float*)d_in[0], (const float*)d_in[3]};
  const float* eat[2] = {(const float*)d_in[1], (const float*)d_in[4]};
  const int*   ei[2] = {(const int*)d_in[2], (const int*)d_in[5]};
  const int N = in_sizes[0] / 128;
  const int E = in_sizes[2] / 2;
  const int Bg = 64;
  const int npg = N / Bg;          // 1000
  const int kq = npg / 2;          // 500

  const float* W1[4] = {(const float*)d_in[9], (const float*)d_in[11],
                        (const float*)d_in[13], (const float*)d_in[15]};
  const float* b1[4] = {(const float*)d_in[10], (const float*)d_in[12],
                        (const float*)d_in[14], (const float*)d_in[16]};
  const float* W2 = (const float*)d_in[17];
  const float* b2 = (const float*)d_in[18];
  const float* W3 = (const float*)d_in[19];
  const float* b3 = (const float*)d_in[20];
  const float* Wsrel  = (const float*)d_in[21];
  const float* bsrel  = (const float*)d_in[22];
  const float* Wsroot = (const float*)d_in[23];
  const float* Wm1 = (const float*)d_in[24];
  const float* bm1 = (const float*)d_in[25];
  const float* Wm2 = (const float*)d_in[26];
  const float* bm2 = (const float*)d_in[27];
  const float* Wm3 = (const float*)d_in[28];
  const float* bm3 = (const float*)d_in[29];
  float* out = (float*)d_out;

  // workspace carve
  char* ws = (char*)d_ws;
  size_t off = 0;
  auto alloc = [&](size_t bytes) -> void* {
    void* p = ws + off;
    off = (off + bytes + 511) & ~(size_t)511;
    return p;
  };
  const size_t nf = (size_t)N * 128 * sizeof(float);
  float* P0 = (float*)alloc(nf);   // S0 / agg2 / agg3
  float* P1 = (float*)alloc(nf);   // S1 / g2
  float* P2 = (float*)alloc(nf);   // S2 / g3
  float* P3 = (float*)alloc(nf);   // S3
  float* P4 = (float*)alloc(nf);   // g1
  float* dinv = (float*)alloc((size_t)5 * N * sizeof(float));
  float* trel = (float*)alloc((size_t)N * sizeof(float));
  float* trot = (float*)alloc((size_t)N * sizeof(float));
  float* sco  = (float*)alloc((size_t)N * sizeof(float));
  int* rowptr = (int*)alloc((size_t)(N + 1) * sizeof(int));
  int* cnt    = (int*)alloc((size_t)N * sizeof(int));
  int* csr    = (int*)alloc((size_t)E * sizeof(int));
  int* csrSrc = (int*)alloc((size_t)E * sizeof(int));
  float4* csrW = (float4*)alloc((size_t)E * sizeof(float4));
  float* csrWO = (float*)alloc((size_t)E * sizeof(float));
  int* bsum   = (int*)alloc(1024);
  float* rbuf = (float*)alloc((size_t)Bg * 768 * sizeof(float));
  if (off > ws_size) return;

  const int nbN = (N + TPB - 1) / TPB;
  const int nbE = (E + TPB - 1) / TPB;
  const int nbGather = N / 8;       // 8000
  const int nbGemm = N / 128;       // 500

  for (int br = 0; br < 2; ++br) {
    const int* erow = ei[br];
    const int* ecol = ei[br] + E;

    // CSR build (deterministic: sorted segments)
    hipMemsetAsync(cnt, 0, (size_t)N * sizeof(int), stream);
    count_k<<<nbE, TPB, 0, stream>>>(ecol, cnt, E);
    scan1_k<<<nbN, TPB, 0, stream>>>(cnt, rowptr, bsum, N);
    scan2_k<<<1, TPB, 0, stream>>>(bsum, nbN);
    scan3_k<<<nbN, TPB, 0, stream>>>(rowptr, bsum, N, E);
    hipMemsetAsync(cnt, 0, (size_t)N * sizeof(int), stream);
    fill_k<<<nbE, TPB, 0, stream>>>(ecol, rowptr, cnt, csr, E);
    sortadj_k<<<nbN, TPB, 0, stream>>>(rowptr, csr, N);
    deg_k<<<nbN, TPB, 0, stream>>>(rowptr, csr, eat[br], dinv, N);
    eresolve_k<<<nbE, TPB, 0, stream>>>(csr, erow, eat[br], dinv, N, E,
                                        csrSrc, csrW, csrWO);

    // conv1: fused 4-channel aggregate of x -> S0..S3, then fused 4-GEMM -> g1
    gather4_k<<<nbGather, 256, 0, stream>>>(
        (const float4*)x[br], rowptr, csrSrc, csrW, dinv, N,
        (float4*)P0, (float4*)P1, (float4*)P2, (float4*)P3);
    gemm4_k<<<nbGemm, 256, 0, stream>>>(P0, P1, P2, P3,
                                        W1[0], W1[1], W1[2], W1[3],
                                        b1[0], b1[1], b1[2], b1[3], P4, N);

    // conv2: aggregate g1 -> P0, g2 = relu(P0 @ W2 + b2) -> P1
    gather1_k<<<nbGather, 256, 0, stream>>>(
        (const float4*)P4, rowptr, csrSrc, csrWO, dinv + (size_t)4 * N, N,
        (float4*)P0);
    gemm_epi<true><<<nbGemm, 256, 0, stream>>>(P0, W2, b2, P1, N);

    // conv3: aggregate g2 -> P0, g3 = P0 @ W3 + b3 -> P2
    gather1_k<<<nbGather, 256, 0, stream>>>(
        (const float4*)P1, rowptr, csrSrc, csrWO, dinv + (size_t)4 * N, N,
        (float4*)P0);
    gemm_epi<false><<<nbGemm, 256, 0, stream>>>(P0, W3, b3, P2, N);

    // score + top-k pool (g1=P4, g2=P1, g3=P2)
    score_a<<<(N + 3) / 4, 256, 0, stream>>>(P4, P1, P2, Wsrel, Wsroot, trel, trot, N);
    score_b<<<nbN, TPB, 0, stream>>>(rowptr, csrSrc, trel, trot, bsrel, sco, N);
    topk_pool<<<Bg, 512, 0, stream>>>(sco, P4, P1, P2, rbuf, br, npg, kq);
  }

  mlp_k<<<Bg, 64, 0, stream>>>(rbuf, Wm1, bm1, Wm2, bm2, Wm3, bm3, out);
}